// Round 5
// baseline (97.393 us; speedup 1.0000x reference)
//
#include <hip/hip_runtime.h>
#include <hip/hip_bf16.h>

// Problem constants
#define B_  2
#define L_  2048
#define C_  1024
#define H_  16
#define K_  32
#define DH_ 64
#define M_  (B_ * L_)   // 4096 rows in all GEMMs

typedef __hip_bfloat16 bf16;
typedef __attribute__((ext_vector_type(4))) float f32x4;
typedef __attribute__((ext_vector_type(8))) short short8;
typedef __attribute__((ext_vector_type(8))) unsigned short u16x8;

__device__ inline unsigned short f2bf(float f) {
    __hip_bfloat16 h = __float2bfloat16(f);  // RTN
    return *reinterpret_cast<unsigned short*>(&h);
}
__device__ inline float bf2f(unsigned short u) {
    return __uint_as_float(((unsigned)u) << 16);
}
__device__ inline void gld_lds16(const bf16* g, bf16* l) {
    __builtin_amdgcn_global_load_lds(
        (const __attribute__((address_space(1))) void*)g,
        (__attribute__((address_space(3))) void*)l,
        16, 0, 0);
}

// ---------------------------------------------------------------------------
// Kernel 1: convert x, Wq, Wk, Wv, Wo from f32 to bf16 (one fused launch).
// ---------------------------------------------------------------------------
__global__ void __launch_bounds__(256) cvt_all(
    const float* __restrict__ x,  const float* __restrict__ wq,
    const float* __restrict__ wk, const float* __restrict__ wv,
    const float* __restrict__ wo,
    bf16* __restrict__ xb,  bf16* __restrict__ wqb, bf16* __restrict__ wkb,
    bf16* __restrict__ wvb, bf16* __restrict__ wob)
{
    int g = blockIdx.x * 256 + threadIdx.x;
    const float* src; bf16* dst; int o;
    if (g < 1048576)      { src = x;  dst = xb;  o = g; }
    else if (g < 1310720) { src = wq; dst = wqb; o = g - 1048576; }
    else if (g < 1572864) { src = wk; dst = wkb; o = g - 1310720; }
    else if (g < 1835008) { src = wv; dst = wvb; o = g - 1572864; }
    else                  { src = wo; dst = wob; o = g - 1835008; }
    float4 f = reinterpret_cast<const float4*>(src)[o];
    ushort4 u;
    u.x = f2bf(f.x); u.y = f2bf(f.y); u.z = f2bf(f.z); u.w = f2bf(f.w);
    reinterpret_cast<ushort4*>(dst)[o] = u;
}

// ---------------------------------------------------------------------------
// Kernel 2/5: NT GEMM  Y = A @ W^T  (m97 128^2 structure — round-2 anchor).
// 128x128 tile, BK=64, 4 waves x (4x4) frags of 16x16x32 bf16 MFMA.
// global_load_lds(16B) with both-sides XOR swizzle.
// ---------------------------------------------------------------------------
struct GemmArgs {
    const bf16* A;
    const bf16* W[3];
    bf16* Yb[3];
    float* Yf;
    float scale0;
};

template<int OUT_F32>
__global__ void __launch_bounds__(256) gemm_nt(GemmArgs ga)
{
    __shared__ bf16 As[128 * 64];   // 16 KiB
    __shared__ bf16 Bs[128 * 64];   // 16 KiB

    const int m0  = blockIdx.x * 128;
    const int nt  = blockIdx.y;
    const int seg = nt >> 3;            // 0..2 (always 0 for OUT_F32)
    const int n0  = (nt & 7) * 128;
    const bf16* __restrict__ A = ga.A;
    const bf16* __restrict__ W = ga.W[seg];
    const float scale = (seg == 0) ? ga.scale0 : 1.0f;

    const int t    = threadIdx.x;
    const int lane = t & 63;
    const int w    = t >> 6;    // wave 0..3
    const int wm   = w >> 1;    // 0..1
    const int wn   = w & 1;     // 0..1

    const int subrow = lane >> 3;   // 0..7 within an 8-row staging inst
    const int kc     = lane & 7;    // 16B chunk 0..7 within a 64-elem k row

    f32x4 acc[4][4] = {};

    for (int kt = 0; kt < 16; ++kt) {
        const int k0 = kt * 64;
        if (kt) __syncthreads();
        #pragma unroll
        for (int i = 0; i < 4; ++i) {
            const int r0  = w * 32 + i * 8;
            const int row = r0 + subrow;
            const int kcs = kc ^ (subrow & 7);   // inverse swizzle on source
            gld_lds16(A + (size_t)(m0 + row) * 1024 + k0 + kcs * 8, As + r0 * 64);
        }
        #pragma unroll
        for (int i = 0; i < 4; ++i) {
            const int r0  = w * 32 + i * 8;
            const int row = r0 + subrow;
            const int kcs = kc ^ (subrow & 7);
            gld_lds16(W + (size_t)(n0 + row) * 1024 + k0 + kcs * 8, Bs + r0 * 64);
        }
        __syncthreads();
        #pragma unroll
        for (int ks = 0; ks < 2; ++ks) {
            short8 af[4], bfv[4];
            #pragma unroll
            for (int mf = 0; mf < 4; ++mf) {
                const int row    = wm * 64 + mf * 16 + (lane & 15);
                const int kchunk = ks * 4 + (lane >> 4);
                const int pc     = kchunk ^ (row & 7);   // swizzled read
                af[mf] = *reinterpret_cast<const short8*>(As + row * 64 + pc * 8);
            }
            #pragma unroll
            for (int nf = 0; nf < 4; ++nf) {
                const int row    = wn * 64 + nf * 16 + (lane & 15);
                const int kchunk = ks * 4 + (lane >> 4);
                const int pc     = kchunk ^ (row & 7);
                bfv[nf] = *reinterpret_cast<const short8*>(Bs + row * 64 + pc * 8);
            }
            #pragma unroll
            for (int mf = 0; mf < 4; ++mf)
                #pragma unroll
                for (int nf = 0; nf < 4; ++nf)
                    acc[mf][nf] = __builtin_amdgcn_mfma_f32_16x16x32_bf16(
                        af[mf], bfv[nf], acc[mf][nf], 0, 0, 0);
        }
    }

    #pragma unroll
    for (int mf = 0; mf < 4; ++mf) {
        #pragma unroll
        for (int nf = 0; nf < 4; ++nf) {
            const int row = m0 + wm * 64 + mf * 16 + ((lane >> 4) << 2);
            const int col = n0 + wn * 64 + nf * 16 + (lane & 15);
            #pragma unroll
            for (int r = 0; r < 4; ++r) {
                const float val = acc[mf][nf][r] * scale;
                if constexpr (OUT_F32) {
                    ga.Yf[(size_t)(row + r) * 1024 + col] = val;
                } else {
                    ga.Yb[seg][(size_t)(row + r) * 1024 + col] = __float2bfloat16(val);
                }
            }
        }
    }
}

// ---------------------------------------------------------------------------
// Kernel 3a: QK pass. One 64-lane wave per (l, slot) with slot = b*4+wg.
// 1-D grid, bid = l*8 + slot  ->  XCD = bid%8 = slot (round-robin heuristic):
// each XCD only gathers from ONE batch's 4 MB k-slab => ~L2-resident.
// Writes normalized softmax probs p[b][l][h][K] (f32, 16 MB) to workspace.
//   lane = (hw<<4)|(half<<3)|c8 ; h = wg*4+hw
// ---------------------------------------------------------------------------
__global__ void __launch_bounds__(64) qk_knn(
    const bf16* __restrict__ qg, const bf16* __restrict__ kg,
    const int* __restrict__ idx, float* __restrict__ pg)
{
    const int bid  = blockIdx.x;
    const int slot = bid & 7;
    const int l    = bid >> 3;
    const int b    = slot >> 2;
    const int wg   = slot & 3;

    const int lane = threadIdx.x;
    const int hw   = lane >> 4;
    const int h    = wg * 4 + hw;
    const int sl   = lane & 15;
    const int half = sl >> 3;
    const int c8   = sl & 7;

    const size_t rowq = (size_t)b * L_ + l;
    const unsigned short* kg16 = reinterpret_cast<const unsigned short*>(kg);
    const size_t hoff = (size_t)h * DH_ + c8 * 8;

    int4 iv[4];
    #pragma unroll
    for (int i = 0; i < 4; ++i)
        iv[i] = reinterpret_cast<const int4*>(idx + l * K_ + half * 16)[i];

    u16x8 qv = *reinterpret_cast<const u16x8*>(
        reinterpret_cast<const unsigned short*>(qg) + rowq * C_ + hoff);
    float qf[8];
    #pragma unroll
    for (int e = 0; e < 8; ++e) qf[e] = bf2f(qv[e]);

    // 16 independent 16B k-gathers + partial dots
    float s[16];
    #pragma unroll
    for (int jj = 0; jj < 16; ++jj) {
        const int4 q4 = iv[jj >> 2];
        const int row = (jj & 3) == 0 ? q4.x : (jj & 3) == 1 ? q4.y
                       : (jj & 3) == 2 ? q4.z : q4.w;
        const u16x8 kv = *reinterpret_cast<const u16x8*>(
            kg16 + ((size_t)b * L_ + row) * C_ + hoff);
        float acc = 0.f;
        #pragma unroll
        for (int e = 0; e < 8; ++e) acc += qf[e] * bf2f(kv[e]);
        s[jj] = acc;
    }

    // reduce across the 8-lane c8 group (xor 1,2,4 stay within the group)
    #pragma unroll
    for (int jj = 0; jj < 16; ++jj) {
        float x = s[jj];
        x += __shfl_xor(x, 1, 16);
        x += __shfl_xor(x, 2, 16);
        x += __shfl_xor(x, 4, 16);
        s[jj] = x;
    }

    // softmax over 32 (cross-half via xor 8)
    float m = s[0];
    #pragma unroll
    for (int jj = 1; jj < 16; ++jj) m = fmaxf(m, s[jj]);
    m = fmaxf(m, __shfl_xor(m, 8, 16));
    float ssum = 0.f;
    #pragma unroll
    for (int jj = 0; jj < 16; ++jj) { s[jj] = __expf(s[jj] - m); ssum += s[jj]; }
    ssum += __shfl_xor(ssum, 8, 16);
    const float inv = 1.0f / ssum;

    // write: lane c8 stores probs {2*c8, 2*c8+1} of its half (float2, 64B/group)
    float2 w2;
    w2.x = s[2 * c8]     * inv;
    w2.y = s[2 * c8 + 1] * inv;
    reinterpret_cast<float2*>(pg + (rowq * H_ + h) * K_ + half * 16)[c8] = w2;
}

// ---------------------------------------------------------------------------
// Kernel 3b: PV pass. Same grid/lane mapping (XCD sees one batch's v-slab).
// v-gathers have no dependency -> single memory epoch.
// ---------------------------------------------------------------------------
__global__ void __launch_bounds__(64) pv_knn(
    const float* __restrict__ pg, const bf16* __restrict__ vg,
    const int* __restrict__ idx, bf16* __restrict__ ao)
{
    const int bid  = blockIdx.x;
    const int slot = bid & 7;
    const int l    = bid >> 3;
    const int b    = slot >> 2;
    const int wg   = slot & 3;

    const int lane = threadIdx.x;
    const int hw   = lane >> 4;
    const int h    = wg * 4 + hw;
    const int sl   = lane & 15;
    const int half = sl >> 3;
    const int c8   = sl & 7;

    const size_t rowq = (size_t)b * L_ + l;
    const unsigned short* vg16 = reinterpret_cast<const unsigned short*>(vg);
    const size_t hoff = (size_t)h * DH_ + c8 * 8;

    int4 iv[4];
    #pragma unroll
    for (int i = 0; i < 4; ++i)
        iv[i] = reinterpret_cast<const int4*>(idx + l * K_ + half * 16)[i];

    // probs for this (h, half): 16 f32, broadcast within the 8-lane group
    const float* pp = pg + (rowq * H_ + h) * K_ + half * 16;
    float4 p4[4];
    #pragma unroll
    for (int i = 0; i < 4; ++i) p4[i] = reinterpret_cast<const float4*>(pp)[i];

    float acc[8] = {0.f, 0.f, 0.f, 0.f, 0.f, 0.f, 0.f, 0.f};
    #pragma unroll
    for (int jj = 0; jj < 16; ++jj) {
        const int4 q4 = iv[jj >> 2];
        const int row = (jj & 3) == 0 ? q4.x : (jj & 3) == 1 ? q4.y
                       : (jj & 3) == 2 ? q4.z : q4.w;
        const float4 pq = p4[jj >> 2];
        const float p = (jj & 3) == 0 ? pq.x : (jj & 3) == 1 ? pq.y
                       : (jj & 3) == 2 ? pq.z : pq.w;
        const u16x8 vv = *reinterpret_cast<const u16x8*>(
            vg16 + ((size_t)b * L_ + row) * C_ + hoff);
        #pragma unroll
        for (int e = 0; e < 8; ++e) acc[e] += p * bf2f(vv[e]);
    }
    #pragma unroll
    for (int e = 0; e < 8; ++e) acc[e] += __shfl_xor(acc[e], 8, 16);

    if (half == 0) {
        u16x8 o;
        #pragma unroll
        for (int e = 0; e < 8; ++e) o[e] = f2bf(acc[e]);
        *reinterpret_cast<u16x8*>(ao + rowq * C_ + hoff) = o;
    }
}

// ---------------------------------------------------------------------------
// Launcher. Workspace layout (bytes):
//   xb 0 (8 MiB) | wqb 8M | wkb 10M | wvb 12M | wob 14M (2 MiB each)
//   q 16M | k 24M | v 32M | ao 40M (8 MiB each) | p 48M (16 MiB) -> 64 MiB
// ---------------------------------------------------------------------------
extern "C" void kernel_launch(void* const* d_in, const int* in_sizes, int n_in,
                              void* d_out, int out_size, void* d_ws, size_t ws_size,
                              hipStream_t stream)
{
    const float* x  = (const float*)d_in[0];
    const int*   idx = (const int*)d_in[1];
    const float* Wq = (const float*)d_in[2];
    const float* Wk = (const float*)d_in[3];
    const float* Wv = (const float*)d_in[4];
    const float* Wo = (const float*)d_in[5];
    float* out = (float*)d_out;

    char* ws = (char*)d_ws;
    bf16* xb  = (bf16*)(ws + 0);
    bf16* wqb = (bf16*)(ws + 8388608);
    bf16* wkb = (bf16*)(ws + 10485760);
    bf16* wvb = (bf16*)(ws + 12582912);
    bf16* wob = (bf16*)(ws + 14680064);
    bf16* qb  = (bf16*)(ws + 16777216);
    bf16* kb  = (bf16*)(ws + 25165824);
    bf16* vb  = (bf16*)(ws + 33554432);
    bf16* ab  = (bf16*)(ws + 41943040);
    float* pb = (float*)(ws + 50331648);

    cvt_all<<<8192, 256, 0, stream>>>(x, Wq, Wk, Wv, Wo, xb, wqb, wkb, wvb, wob);

    GemmArgs g1;
    g1.A = xb;
    g1.W[0] = wqb; g1.W[1] = wkb; g1.W[2] = wvb;
    g1.Yb[0] = qb; g1.Yb[1] = kb; g1.Yb[2] = vb;
    g1.Yf = nullptr;
    g1.scale0 = 0.125f;   // 1/sqrt(Dh)
    gemm_nt<0><<<dim3(32, 24), 256, 0, stream>>>(g1);

    qk_knn<<<L_ * 8, 64, 0, stream>>>(qb, kb, idx, pb);
    pv_knn<<<L_ * 8, 64, 0, stream>>>(pb, vb, idx, ab);

    GemmArgs g2;
    g2.A = ab;
    g2.W[0] = wob; g2.W[1] = wob; g2.W[2] = wob;
    g2.Yb[0] = nullptr; g2.Yb[1] = nullptr; g2.Yb[2] = nullptr;
    g2.Yf = out;
    g2.scale0 = 1.0f;
    gemm_nt<1><<<dim3(32, 8), 256, 0, stream>>>(g2);
}

// Round 6
// 85.530 us; speedup vs baseline: 1.1387x; 1.1387x over previous
//
#include <hip/hip_runtime.h>
#include <hip/hip_bf16.h>

// Problem constants
#define B_  2
#define L_  2048
#define C_  1024
#define H_  16
#define K_  32
#define DH_ 64
#define M_  (B_ * L_)   // 4096 rows in all GEMMs

typedef __hip_bfloat16 bf16;
typedef __attribute__((ext_vector_type(4))) float f32x4;
typedef __attribute__((ext_vector_type(8))) short short8;
typedef __attribute__((ext_vector_type(8))) unsigned short u16x8;

__device__ inline unsigned short f2bf(float f) {
    __hip_bfloat16 h = __float2bfloat16(f);  // RTN
    return *reinterpret_cast<unsigned short*>(&h);
}
__device__ inline float bf2f(unsigned short u) {
    return __uint_as_float(((unsigned)u) << 16);
}
__device__ inline void gld_lds16(const bf16* g, bf16* l) {
    __builtin_amdgcn_global_load_lds(
        (const __attribute__((address_space(1))) void*)g,
        (__attribute__((address_space(3))) void*)l,
        16, 0, 0);
}

// ---------------------------------------------------------------------------
// Kernel 1: convert x, Wq, Wk, Wv, Wo from f32 to bf16 (one fused launch).
// Memory-bound at ~50 MB -> ~8 us (at BW roofline).
// ---------------------------------------------------------------------------
__global__ void __launch_bounds__(256) cvt_all(
    const float* __restrict__ x,  const float* __restrict__ wq,
    const float* __restrict__ wk, const float* __restrict__ wv,
    const float* __restrict__ wo,
    bf16* __restrict__ xb,  bf16* __restrict__ wqb, bf16* __restrict__ wkb,
    bf16* __restrict__ wvb, bf16* __restrict__ wob)
{
    int g = blockIdx.x * 256 + threadIdx.x;
    const float* src; bf16* dst; int o;
    if (g < 1048576)      { src = x;  dst = xb;  o = g; }
    else if (g < 1310720) { src = wq; dst = wqb; o = g - 1048576; }
    else if (g < 1572864) { src = wk; dst = wkb; o = g - 1310720; }
    else if (g < 1835008) { src = wv; dst = wvb; o = g - 1572864; }
    else                  { src = wo; dst = wob; o = g - 1835008; }
    float4 f = reinterpret_cast<const float4*>(src)[o];
    ushort4 u;
    u.x = f2bf(f.x); u.y = f2bf(f.y); u.z = f2bf(f.z); u.w = f2bf(f.w);
    reinterpret_cast<ushort4*>(dst)[o] = u;
}

// ---------------------------------------------------------------------------
// Kernel 2: QKV NT GEMM  Y = x @ [Wq|Wk|Wv]^T  (m97 128^2 structure).
// grid (32, 24) = 768 blocks = 3/CU (implicit wave-level overlap regime).
// global_load_lds(16B) with both-sides XOR swizzle.
// ---------------------------------------------------------------------------
struct GemmArgs {
    const bf16* A;
    const bf16* W[3];
    bf16* Yb[3];
    float scale0;
};

__global__ void __launch_bounds__(256) gemm_qkv(GemmArgs ga)
{
    __shared__ bf16 As[128 * 64];   // 16 KiB
    __shared__ bf16 Bs[128 * 64];   // 16 KiB

    const int m0  = blockIdx.x * 128;
    const int nt  = blockIdx.y;
    const int seg = nt >> 3;            // 0..2 -> Wq/Wk/Wv
    const int n0  = (nt & 7) * 128;
    const bf16* __restrict__ A = ga.A;
    const bf16* __restrict__ W = ga.W[seg];
    const float scale = (seg == 0) ? ga.scale0 : 1.0f;

    const int t    = threadIdx.x;
    const int lane = t & 63;
    const int w    = t >> 6;    // wave 0..3
    const int wm   = w >> 1;    // 0..1
    const int wn   = w & 1;     // 0..1

    const int subrow = lane >> 3;   // 0..7 within an 8-row staging inst
    const int kc     = lane & 7;    // 16B chunk 0..7 within a 64-elem k row

    f32x4 acc[4][4] = {};

    for (int kt = 0; kt < 16; ++kt) {
        const int k0 = kt * 64;
        if (kt) __syncthreads();
        #pragma unroll
        for (int i = 0; i < 4; ++i) {
            const int r0  = w * 32 + i * 8;
            const int row = r0 + subrow;
            const int kcs = kc ^ (subrow & 7);   // inverse swizzle on source
            gld_lds16(A + (size_t)(m0 + row) * 1024 + k0 + kcs * 8, As + r0 * 64);
        }
        #pragma unroll
        for (int i = 0; i < 4; ++i) {
            const int r0  = w * 32 + i * 8;
            const int row = r0 + subrow;
            const int kcs = kc ^ (subrow & 7);
            gld_lds16(W + (size_t)(n0 + row) * 1024 + k0 + kcs * 8, Bs + r0 * 64);
        }
        __syncthreads();
        #pragma unroll
        for (int ks = 0; ks < 2; ++ks) {
            short8 af[4], bfv[4];
            #pragma unroll
            for (int mf = 0; mf < 4; ++mf) {
                const int row    = wm * 64 + mf * 16 + (lane & 15);
                const int kchunk = ks * 4 + (lane >> 4);
                const int pc     = kchunk ^ (row & 7);   // swizzled read
                af[mf] = *reinterpret_cast<const short8*>(As + row * 64 + pc * 8);
            }
            #pragma unroll
            for (int nf = 0; nf < 4; ++nf) {
                const int row    = wn * 64 + nf * 16 + (lane & 15);
                const int kchunk = ks * 4 + (lane >> 4);
                const int pc     = kchunk ^ (row & 7);
                bfv[nf] = *reinterpret_cast<const short8*>(Bs + row * 64 + pc * 8);
            }
            #pragma unroll
            for (int mf = 0; mf < 4; ++mf)
                #pragma unroll
                for (int nf = 0; nf < 4; ++nf)
                    acc[mf][nf] = __builtin_amdgcn_mfma_f32_16x16x32_bf16(
                        af[mf], bfv[nf], acc[mf][nf], 0, 0, 0);
        }
    }

    #pragma unroll
    for (int mf = 0; mf < 4; ++mf) {
        #pragma unroll
        for (int nf = 0; nf < 4; ++nf) {
            const int row = m0 + wm * 64 + mf * 16 + ((lane >> 4) << 2);
            const int col = n0 + wn * 64 + nf * 16 + (lane & 15);
            #pragma unroll
            for (int r = 0; r < 4; ++r)
                ga.Yb[seg][(size_t)(row + r) * 1024 + col] =
                    __float2bfloat16(acc[mf][nf][r] * scale);
        }
    }
}

// ---------------------------------------------------------------------------
// Kernel 4: output projection NT GEMM, 128x64 tile -> grid (32,16) = 512
// blocks = 2/CU (restores cross-block overlap of the barrier drain that a
// 1-block/CU 128^2 grid fully exposes).  f32 output to d_out.
// 4 waves: wm = 64-row half, wn = 32-col half; per-wave C = 64x32 (4x2 frags).
// ---------------------------------------------------------------------------
__global__ void __launch_bounds__(256) gemm_out(
    const bf16* __restrict__ A, const bf16* __restrict__ W,
    float* __restrict__ Yf)
{
    __shared__ bf16 As[128 * 64];   // 16 KiB
    __shared__ bf16 Bs[64 * 64];    // 8 KiB

    const int m0 = blockIdx.x * 128;
    const int n0 = blockIdx.y * 64;

    const int t    = threadIdx.x;
    const int lane = t & 63;
    const int w    = t >> 6;
    const int wm   = w >> 1;    // 0..1
    const int wn   = w & 1;     // 0..1

    const int subrow = lane >> 3;
    const int kc     = lane & 7;

    f32x4 acc[4][2] = {};

    for (int kt = 0; kt < 16; ++kt) {
        const int k0 = kt * 64;
        if (kt) __syncthreads();
        // A tile: 128 rows, wave stages rows [w*32, w*32+32)
        #pragma unroll
        for (int i = 0; i < 4; ++i) {
            const int r0  = w * 32 + i * 8;
            const int row = r0 + subrow;
            const int kcs = kc ^ (subrow & 7);
            gld_lds16(A + (size_t)(m0 + row) * 1024 + k0 + kcs * 8, As + r0 * 64);
        }
        // B tile: 64 rows, wave stages rows [w*16, w*16+16)
        #pragma unroll
        for (int i = 0; i < 2; ++i) {
            const int r0  = w * 16 + i * 8;
            const int row = r0 + subrow;
            const int kcs = kc ^ (subrow & 7);
            gld_lds16(W + (size_t)(n0 + row) * 1024 + k0 + kcs * 8, Bs + r0 * 64);
        }
        __syncthreads();
        #pragma unroll
        for (int ks = 0; ks < 2; ++ks) {
            short8 af[4], bfv[2];
            #pragma unroll
            for (int mf = 0; mf < 4; ++mf) {
                const int row    = wm * 64 + mf * 16 + (lane & 15);
                const int kchunk = ks * 4 + (lane >> 4);
                const int pc     = kchunk ^ (row & 7);
                af[mf] = *reinterpret_cast<const short8*>(As + row * 64 + pc * 8);
            }
            #pragma unroll
            for (int nf = 0; nf < 2; ++nf) {
                const int row    = wn * 32 + nf * 16 + (lane & 15);
                const int kchunk = ks * 4 + (lane >> 4);
                const int pc     = kchunk ^ (row & 7);
                bfv[nf] = *reinterpret_cast<const short8*>(Bs + row * 64 + pc * 8);
            }
            #pragma unroll
            for (int mf = 0; mf < 4; ++mf)
                #pragma unroll
                for (int nf = 0; nf < 2; ++nf)
                    acc[mf][nf] = __builtin_amdgcn_mfma_f32_16x16x32_bf16(
                        af[mf], bfv[nf], acc[mf][nf], 0, 0, 0);
        }
    }

    #pragma unroll
    for (int mf = 0; mf < 4; ++mf) {
        #pragma unroll
        for (int nf = 0; nf < 2; ++nf) {
            const int row = m0 + wm * 64 + mf * 16 + ((lane >> 4) << 2);
            const int col = n0 + wn * 32 + nf * 16 + (lane & 15);
            #pragma unroll
            for (int r = 0; r < 4; ++r)
                Yf[(size_t)(row + r) * 1024 + col] = acc[mf][nf][r];
        }
    }
}

// ---------------------------------------------------------------------------
// Kernel 3: K=32 neighbor attention — wave-synchronous, no LDS, no barriers.
// NEW (round 6): 4-wave blocks (256 threads): wave ww handles l = l0+ww for
// the block's slot = b*4+wg.  Same bid%8 = slot XCD pinning (grid x = slot);
// 4-wave workgroups lift the per-CU workgroup cap from ~16 waves/CU to
// ~32 waves/CU at 44 VGPR -> 2x gathers in flight per CU.
//   lane = (hw<<4)|(half<<3)|c8 ; h = wg*4+hw ; d-chunk = c8*8 (16B)
// ---------------------------------------------------------------------------
__global__ void __launch_bounds__(256) attn_knn(
    const bf16* __restrict__ qg, const bf16* __restrict__ kg,
    const bf16* __restrict__ vg, const int* __restrict__ idx,
    bf16* __restrict__ ao)
{
    const int slot = blockIdx.x;      // 0..7 -> XCD (bid%8 heuristic)
    const int b    = slot >> 2;
    const int wg   = slot & 3;
    const int l    = blockIdx.y * 4 + (threadIdx.x >> 6);

    const int lane = threadIdx.x & 63;
    const int hw   = lane >> 4;       // head within group
    const int h    = wg * 4 + hw;
    const int sl   = lane & 15;
    const int half = sl >> 3;
    const int c8   = sl & 7;

    const size_t rowq = (size_t)b * L_ + l;
    const unsigned short* kg16 = reinterpret_cast<const unsigned short*>(kg);
    const unsigned short* vg16 = reinterpret_cast<const unsigned short*>(vg);
    const size_t hoff = (size_t)h * DH_ + c8 * 8;

    int4 iv[4];
    #pragma unroll
    for (int i = 0; i < 4; ++i)
        iv[i] = reinterpret_cast<const int4*>(idx + l * K_ + half * 16)[i];

    u16x8 qv = *reinterpret_cast<const u16x8*>(
        reinterpret_cast<const unsigned short*>(qg) + rowq * C_ + hoff);
    float qf[8];
    #pragma unroll
    for (int e = 0; e < 8; ++e) qf[e] = bf2f(qv[e]);

    // ---- QK^T partial dots (16 independent 16B gathers) ----
    float s[16];
    #pragma unroll
    for (int jj = 0; jj < 16; ++jj) {
        const int4 q4 = iv[jj >> 2];
        const int row = (jj & 3) == 0 ? q4.x : (jj & 3) == 1 ? q4.y
                       : (jj & 3) == 2 ? q4.z : q4.w;
        const u16x8 kv = *reinterpret_cast<const u16x8*>(
            kg16 + ((size_t)b * L_ + row) * C_ + hoff);
        float acc = 0.f;
        #pragma unroll
        for (int e = 0; e < 8; ++e) acc += qf[e] * bf2f(kv[e]);
        s[jj] = acc;
    }

    // reduce partial dots across the 8-lane c8 group
    #pragma unroll
    for (int jj = 0; jj < 16; ++jj) {
        float x = s[jj];
        x += __shfl_xor(x, 1, 16);
        x += __shfl_xor(x, 2, 16);
        x += __shfl_xor(x, 4, 16);
        s[jj] = x;   // full score for j = half*16 + jj, in all 8 lanes
    }

    // ---- softmax in registers; 1/sum deferred to the store ----
    float m = s[0];
    #pragma unroll
    for (int jj = 1; jj < 16; ++jj) m = fmaxf(m, s[jj]);
    m = fmaxf(m, __shfl_xor(m, 8, 16));
    float ssum = 0.f;
    #pragma unroll
    for (int jj = 0; jj < 16; ++jj) { s[jj] = __expf(s[jj] - m); ssum += s[jj]; }
    ssum += __shfl_xor(ssum, 8, 16);
    const float inv = 1.0f / ssum;

    // ---- PV (16 independent 16B gathers) ----
    float acc[8] = {0.f, 0.f, 0.f, 0.f, 0.f, 0.f, 0.f, 0.f};
    #pragma unroll
    for (int jj = 0; jj < 16; ++jj) {
        const int4 q4 = iv[jj >> 2];
        const int row = (jj & 3) == 0 ? q4.x : (jj & 3) == 1 ? q4.y
                       : (jj & 3) == 2 ? q4.z : q4.w;
        const u16x8 vv = *reinterpret_cast<const u16x8*>(
            vg16 + ((size_t)b * L_ + row) * C_ + hoff);
        const float p = s[jj];
        #pragma unroll
        for (int e = 0; e < 8; ++e) acc[e] += p * bf2f(vv[e]);
    }
    #pragma unroll
    for (int e = 0; e < 8; ++e) acc[e] += __shfl_xor(acc[e], 8, 16);

    if (half == 0) {
        u16x8 o;
        #pragma unroll
        for (int e = 0; e < 8; ++e) o[e] = f2bf(acc[e] * inv);
        *reinterpret_cast<u16x8*>(ao + rowq * C_ + hoff) = o;
    }
}

// ---------------------------------------------------------------------------
// Launcher. Workspace layout (bytes):
//   xb 0 (8 MiB) | wqb 8M | wkb 10M | wvb 12M | wob 14M (2 MiB each)
//   q 16M | k 24M | v 32M | ao 40M  (8 MiB each)  -> total 48 MiB
// ---------------------------------------------------------------------------
extern "C" void kernel_launch(void* const* d_in, const int* in_sizes, int n_in,
                              void* d_out, int out_size, void* d_ws, size_t ws_size,
                              hipStream_t stream)
{
    const float* x  = (const float*)d_in[0];
    const int*   idx = (const int*)d_in[1];
    const float* Wq = (const float*)d_in[2];
    const float* Wk = (const float*)d_in[3];
    const float* Wv = (const float*)d_in[4];
    const float* Wo = (const float*)d_in[5];
    float* out = (float*)d_out;

    char* ws = (char*)d_ws;
    bf16* xb  = (bf16*)(ws + 0);
    bf16* wqb = (bf16*)(ws + 8388608);
    bf16* wkb = (bf16*)(ws + 10485760);
    bf16* wvb = (bf16*)(ws + 12582912);
    bf16* wob = (bf16*)(ws + 14680064);
    bf16* qb  = (bf16*)(ws + 16777216);
    bf16* kb  = (bf16*)(ws + 25165824);
    bf16* vb  = (bf16*)(ws + 33554432);
    bf16* ab  = (bf16*)(ws + 41943040);

    cvt_all<<<8192, 256, 0, stream>>>(x, Wq, Wk, Wv, Wo, xb, wqb, wkb, wvb, wob);

    GemmArgs g1;
    g1.A = xb;
    g1.W[0] = wqb; g1.W[1] = wkb; g1.W[2] = wvb;
    g1.Yb[0] = qb; g1.Yb[1] = kb; g1.Yb[2] = vb;
    g1.scale0 = 0.125f;   // 1/sqrt(Dh)
    gemm_qkv<<<dim3(32, 24), 256, 0, stream>>>(g1);

    attn_knn<<<dim3(8, 512), 256, 0, stream>>>(qb, kb, vb, idx, ab);

    gemm_out<<<dim3(32, 16), 256, 0, stream>>>(ab, wob, out);
}